// Round 1
// baseline (503.196 us; speedup 1.0000x reference)
//
#include <hip/hip_runtime.h>
#include <math.h>

// Problem constants
#define NN 64     // nodes
#define BB 256    // batch
#define CC 256    // channels
#define MM 128    // h dim
#define HH 4      // heads
#define HD 64     // head dim
#define TT 8      // time slots

// ---------------------------------------------------------------------------
// K0: W_qk[m][c'] = sum_c bq_w[m][c] * bk_w[c'][c]   (= bq_w @ bk_w^T)
//     w_qb[c']   = sum_c bq_b[c]    * bk_w[c'][c]
// Folds bq and bq@bk_w^T into one GEMM later. bk_b cancels in softmax over t.
// ---------------------------------------------------------------------------
__global__ __launch_bounds__(256) void wqk_kernel(
    const float* __restrict__ bq_w, const float* __restrict__ bq_b,
    const float* __restrict__ bk_w, float* __restrict__ wqk,
    float* __restrict__ wqb)
{
    __shared__ float arow[CC];
    __shared__ float brow[CC];
    const int m  = blockIdx.x;
    const int c1 = threadIdx.x;
    arow[c1] = bq_w[m * CC + c1];
    brow[c1] = bq_b[c1];
    __syncthreads();
    const float* bk = &bk_w[(long)c1 * CC];
    float s = 0.f, sb = 0.f;
    for (int c = 0; c < CC; ++c) {
        float bkv = bk[c];
        s  += arow[c] * bkv;
        sb += brow[c] * bkv;
    }
    wqk[m * CC + c1] = s;
    if (m == 0) wqb[c1] = sb;
}

// ---------------------------------------------------------------------------
// K1: graph attention, one block per (b,h). N=64 nodes, HD=64.
// Computes logits (QK^T/8 + bond + ctrl), self-mask, exact top-8/row,
// softmax, writes attn [B,H,N,N] and msgs [B,N,C] (head-merged).
// ---------------------------------------------------------------------------
__global__ __launch_bounds__(256) void graph_attn_kernel(
    const float* __restrict__ q, const float* __restrict__ k,
    const float* __restrict__ v, const float* __restrict__ send,
    const float* __restrict__ ctrl, const float* __restrict__ bond,
    float* __restrict__ attn_out, float* __restrict__ msgs_out)
{
    __shared__ float Qs[NN][HD + 1];
    __shared__ float Ks[NN][HD + 1];   // reused as Vs after logits
    __shared__ float Ls[NN][NN + 1];
    __shared__ float ctrl_s[NN];
    __shared__ float thr_s[NN], max_s[NN], sum_s[NN], part_s[256];

    const int tid = threadIdx.x;
    const int b   = blockIdx.x >> 2;
    const int h   = blockIdx.x & 3;
    const long base = (long)b * CC + h * HD;

    for (int i = tid; i < NN * HD; i += 256) {
        const int n = i >> 6, d = i & 63;
        const long gi = (long)n * (BB * CC) + base + d;
        Qs[n][d] = q[gi];
        Ks[n][d] = k[gi];
    }
    if (tid < NN) ctrl_s[tid] = ctrl[(long)tid * (BB * HH) + b * HH + h];
    __syncthreads();

    const int n  = tid >> 2;
    const int m0 = (tid & 3) << 4;
    #pragma unroll 4
    for (int mi = 0; mi < 16; ++mi) {
        const int m = m0 + mi;
        float s = 0.f;
        #pragma unroll
        for (int d = 0; d < HD; ++d) s += Qs[n][d] * Ks[m][d];
        float lg = s * 0.125f + bond[n * NN + m] + ctrl_s[m];
        if (m == n) lg = -INFINITY;
        Ls[n][m] = lg;
    }
    __syncthreads();

    // Reload Ks as Vg = v*send (Ks dead now); wave0 does top-8 concurrently.
    for (int i = tid; i < NN * HD; i += 256) {
        const int n2 = i >> 6, d = i & 63;
        const long gi = (long)n2 * (BB * CC) + base + d;
        Ks[n2][d] = v[gi] * send[gi];
    }
    if (tid < NN) {
        float t8[8];
        #pragma unroll
        for (int i = 0; i < 8; ++i) t8[i] = -INFINITY;
        for (int m = 0; m < NN; ++m) {
            const float x = Ls[tid][m];
            float mv = t8[0]; int am = 0;
            #pragma unroll
            for (int i = 1; i < 8; ++i) if (t8[i] < mv) { mv = t8[i]; am = i; }
            if (x > mv) t8[am] = x;
        }
        float thr = t8[0], mx = t8[0];
        #pragma unroll
        for (int i = 1; i < 8; ++i) { thr = fminf(thr, t8[i]); mx = fmaxf(mx, t8[i]); }
        thr_s[tid] = thr; max_s[tid] = mx;
    }
    __syncthreads();

    float ev[16];
    {
        const float thr = thr_s[n], mx = max_s[n];
        float ls = 0.f;
        #pragma unroll
        for (int mi = 0; mi < 16; ++mi) {
            const float x = Ls[n][m0 + mi];
            const float e = (x >= thr) ? __expf(x - mx) : 0.f;
            ev[mi] = e; ls += e;
        }
        part_s[tid] = ls;
    }
    __syncthreads();
    if ((tid & 3) == 0)
        sum_s[n] = part_s[tid] + part_s[tid + 1] + part_s[tid + 2] + part_s[tid + 3];
    __syncthreads();
    {
        const float inv = 1.f / sum_s[n];
        float* ag = attn_out + ((long)(b * HH + h) * NN + n) * NN + m0;
        #pragma unroll
        for (int mi = 0; mi < 16; ++mi) { ev[mi] *= inv; Ls[n][m0 + mi] = ev[mi]; }
        #pragma unroll
        for (int mi = 0; mi < 16; mi += 4)
            *(float4*)(ag + mi) = make_float4(ev[mi], ev[mi+1], ev[mi+2], ev[mi+3]);
    }
    __syncthreads();

    // msgs[n][ds..ds+15] = sum_m attn[n][m] * Vg[m][ds..]
    float accm[16];
    #pragma unroll
    for (int i = 0; i < 16; ++i) accm[i] = 0.f;
    const int ds = (tid & 3) << 4;
    for (int m = 0; m < NN; ++m) {
        const float a = Ls[n][m];
        #pragma unroll
        for (int i = 0; i < 16; ++i) accm[i] += a * Ks[m][ds + i];
    }
    float* mg = msgs_out + (long)b * (NN * CC) + (long)n * CC + h * HD + ds;
    #pragma unroll
    for (int i = 0; i < 16; i += 4)
        *(float4*)(mg + i) = make_float4(accm[i], accm[i+1], accm[i+2], accm[i+3]);
}

// ---------------------------------------------------------------------------
// Shared tiled fp32 GEMM body: 64x64 block, BK=32, 256 threads, 4x4 micro.
// A: [M, KDIM] row-major; B: [KDIM, 256] row-major.
// ---------------------------------------------------------------------------
template <int KDIM>
__device__ __forceinline__ void gemm_tile(
    const float* __restrict__ A, const float* __restrict__ B,
    int row0, int col0, int tid,
    float (&acc)[4][4], float (*As)[36], float (*Bs)[68])
{
    const int arow = tid >> 2, ac0 = (tid & 3) << 3;
    const int brow = tid >> 3, bc0 = (tid & 7) << 3;
    const int ty = tid >> 4, tx = tid & 15;
    for (int k0 = 0; k0 < KDIM; k0 += 32) {
        const float4 a0 = *(const float4*)(A + (long)(row0 + arow) * KDIM + k0 + ac0);
        const float4 a1 = *(const float4*)(A + (long)(row0 + arow) * KDIM + k0 + ac0 + 4);
        const float4 b0 = *(const float4*)(B + (long)(k0 + brow) * CC + col0 + bc0);
        const float4 b1 = *(const float4*)(B + (long)(k0 + brow) * CC + col0 + bc0 + 4);
        *(float4*)&As[arow][ac0]     = a0;
        *(float4*)&As[arow][ac0 + 4] = a1;
        *(float4*)&Bs[brow][bc0]     = b0;
        *(float4*)&Bs[brow][bc0 + 4] = b1;
        __syncthreads();
        #pragma unroll
        for (int kk = 0; kk < 32; ++kk) {
            float av[4], bv[4];
            #pragma unroll
            for (int i = 0; i < 4; ++i) av[i] = As[ty * 4 + i][kk];
            #pragma unroll
            for (int j = 0; j < 4; ++j) bv[j] = Bs[kk][tx * 4 + j];
            #pragma unroll
            for (int i = 0; i < 4; ++i)
                #pragma unroll
                for (int j = 0; j < 4; ++j)
                    acc[i][j] += av[i] * bv[j];
        }
        __syncthreads();
    }
}

// K3: msgs2 = (msgs @ out_w + out_b) * recv -> new_buf[:,:,7,:]
__global__ __launch_bounds__(256) void msgs2_kernel(
    const float* __restrict__ A, const float* __restrict__ Bw,
    const float* __restrict__ bias, const float* __restrict__ recv,
    float* __restrict__ newbuf)
{
    __shared__ float As[64][36];
    __shared__ float Bs[32][68];
    const int tid = threadIdx.x;
    const int row0 = (blockIdx.x >> 2) * 64;
    const int col0 = (blockIdx.x & 3) * 64;
    float acc[4][4] = {};
    gemm_tile<CC>(A, Bw, row0, col0, tid, acc, As, Bs);
    const int ty = tid >> 4, tx = tid & 15;
    const int cg = col0 + tx * 4;
    const float4 b4 = *(const float4*)(bias + cg);
    #pragma unroll
    for (int i = 0; i < 4; ++i) {
        const int r = row0 + ty * 4 + i;
        const int b = r >> 6, n = r & 63;
        const float4 rg = *(const float4*)(recv + (long)n * (BB * CC) + (long)b * CC + cg);
        float4 o;
        o.x = (acc[i][0] + b4.x) * rg.x;
        o.y = (acc[i][1] + b4.y) * rg.y;
        o.z = (acc[i][2] + b4.z) * rg.z;
        o.w = (acc[i][3] + b4.w) * rg.w;
        *(float4*)(newbuf + ((long)(n * BB + b) * TT + 7) * CC + cg) = o;
    }
}

// K4: bq2 = h @ W_qk + w_qb   (rows n*B+b)
__global__ __launch_bounds__(256) void bq2_kernel(
    const float* __restrict__ hmat, const float* __restrict__ wqk,
    const float* __restrict__ wqb, float* __restrict__ bq2)
{
    __shared__ float As[64][36];
    __shared__ float Bs[32][68];
    const int tid = threadIdx.x;
    const int row0 = (blockIdx.x >> 2) * 64;
    const int col0 = (blockIdx.x & 3) * 64;
    float acc[4][4] = {};
    gemm_tile<MM>(hmat, wqk, row0, col0, tid, acc, As, Bs);
    const int ty = tid >> 4, tx = tid & 15;
    const int cg = col0 + tx * 4;
    const float4 b4 = *(const float4*)(wqb + cg);
    #pragma unroll
    for (int i = 0; i < 4; ++i) {
        const int r = row0 + ty * 4 + i;
        float4 o;
        o.x = acc[i][0] + b4.x;
        o.y = acc[i][1] + b4.y;
        o.z = acc[i][2] + b4.z;
        o.w = acc[i][3] + b4.w;
        *(float4*)(bq2 + (long)r * CC + cg) = o;
    }
}

// K5: temporal attention + buffer shift. One wave per (n,b) pair.
__global__ __launch_bounds__(256) void temporal_kernel(
    const float* __restrict__ buffers, const float* __restrict__ bq2,
    const float* __restrict__ decay_logit,
    float* __restrict__ newbuf, float* __restrict__ acc_out,
    float* __restrict__ s_out)
{
    const int tid  = threadIdx.x;
    const int pair = blockIdx.x * 4 + (tid >> 6);
    const int lane = tid & 63;
    const float dl    = decay_logit[0];
    const float decay = 1.f / (1.f + __expf(-dl));

    const long base = (long)pair * (TT * CC);
    float r[8][4];
    #pragma unroll
    for (int t = 0; t < 7; ++t)
        #pragma unroll
        for (int i = 0; i < 4; ++i)
            r[t][i] = buffers[base + (long)(t + 1) * CC + lane + 64 * i];
    #pragma unroll
    for (int i = 0; i < 4; ++i)
        r[7][i] = newbuf[base + 7L * CC + lane + 64 * i];
    // buffer shift write-through (t = 0..6)
    #pragma unroll
    for (int t = 0; t < 7; ++t)
        #pragma unroll
        for (int i = 0; i < 4; ++i)
            newbuf[base + (long)t * CC + lane + 64 * i] = r[t][i];

    float qv[4];
    #pragma unroll
    for (int i = 0; i < 4; ++i) qv[i] = bq2[(long)pair * CC + lane + 64 * i];

    float pz[8];
    #pragma unroll
    for (int t = 0; t < 8; ++t) {
        float p = 0.f;
        #pragma unroll
        for (int i = 0; i < 4; ++i) p += qv[i] * r[t][i];
        pz[t] = p;
    }
    #pragma unroll
    for (int off = 32; off >= 1; off >>= 1)
        #pragma unroll
        for (int t = 0; t < 8; ++t)
            pz[t] += __shfl_xor(pz[t], off);

    float mx = -INFINITY;
    #pragma unroll
    for (int t = 0; t < 8; ++t) { pz[t] *= 0.0625f; mx = fmaxf(mx, pz[t]); }
    float e[8], sum = 0.f;
    #pragma unroll
    for (int t = 0; t < 8; ++t) { e[t] = __expf(pz[t] - mx); sum += e[t]; }
    const float inv = 1.f / sum;

    float w[8], ssum = 0.f, p = decay;
    #pragma unroll
    for (int t = 7; t >= 0; --t) { w[t] = e[t] * inv * p; p *= decay; ssum += w[t]; }

    #pragma unroll
    for (int i = 0; i < 4; ++i) {
        float a = 0.f;
        #pragma unroll
        for (int t = 0; t < 8; ++t) a += w[t] * r[t][i];
        acc_out[(long)pair * CC + lane + 64 * i] = a;
    }
    if (lane == 0) s_out[pair] = ssum;
}

// K6: readout = acc @ bv_w + s * bv_b
__global__ __launch_bounds__(256) void readout_kernel(
    const float* __restrict__ A, const float* __restrict__ bvw,
    const float* __restrict__ svec, const float* __restrict__ bvb,
    float* __restrict__ out)
{
    __shared__ float As[64][36];
    __shared__ float Bs[32][68];
    const int tid = threadIdx.x;
    const int row0 = (blockIdx.x >> 2) * 64;
    const int col0 = (blockIdx.x & 3) * 64;
    float acc[4][4] = {};
    gemm_tile<CC>(A, bvw, row0, col0, tid, acc, As, Bs);
    const int ty = tid >> 4, tx = tid & 15;
    const int cg = col0 + tx * 4;
    const float4 b4 = *(const float4*)(bvb + cg);
    #pragma unroll
    for (int i = 0; i < 4; ++i) {
        const int r = row0 + ty * 4 + i;
        const float s = svec[r];
        float4 o;
        o.x = acc[i][0] + s * b4.x;
        o.y = acc[i][1] + s * b4.y;
        o.z = acc[i][2] + s * b4.z;
        o.w = acc[i][3] + s * b4.w;
        *(float4*)(out + (long)r * CC + cg) = o;
    }
}

// ---------------------------------------------------------------------------
extern "C" void kernel_launch(void* const* d_in, const int* in_sizes, int n_in,
                              void* d_out, int out_size, void* d_ws, size_t ws_size,
                              hipStream_t stream) {
    const float* q     = (const float*)d_in[0];
    const float* k     = (const float*)d_in[1];
    const float* v     = (const float*)d_in[2];
    const float* send  = (const float*)d_in[3];
    const float* recv  = (const float*)d_in[4];
    const float* ctrl  = (const float*)d_in[5];
    const float* hmat  = (const float*)d_in[6];
    const float* bufs  = (const float*)d_in[7];
    const float* bond  = (const float*)d_in[8];
    const float* out_w = (const float*)d_in[9];
    const float* out_b = (const float*)d_in[10];
    const float* bq_w  = (const float*)d_in[11];
    const float* bq_b  = (const float*)d_in[12];
    const float* bk_w  = (const float*)d_in[13];
    // d_in[14] = bk_b: constant shift over t -> cancels in softmax, unused.
    const float* bv_w  = (const float*)d_in[15];
    const float* bv_b  = (const float*)d_in[16];
    const float* dlog  = (const float*)d_in[17];

    float* out      = (float*)d_out;
    float* readout  = out;                          // [N,B,C]     4,194,304
    float* newbuf   = out + 4194304;                // [N,B,T,C]  33,554,432
    float* attn     = out + 4194304 + 33554432;     // [B,H,N,N]   4,194,304

    float* ws       = (float*)d_ws;
    float* ws_msgs  = ws;                 // [B,N,C]  4,194,304
    float* ws_bq2   = ws + 4194304;       // [N,B,C]  4,194,304
    float* ws_acc   = ws + 8388608;       // [N,B,C]  4,194,304
    float* ws_s     = ws + 12582912;      // [N,B]       16,384
    float* ws_wqk   = ws + 12599296;      // [M,C]       32,768
    float* ws_wqb   = ws + 12632064;      // [C]            256

    wqk_kernel<<<MM, 256, 0, stream>>>(bq_w, bq_b, bk_w, ws_wqk, ws_wqb);
    graph_attn_kernel<<<BB * HH, 256, 0, stream>>>(q, k, v, send, ctrl, bond,
                                                   attn, ws_msgs);
    msgs2_kernel<<<(BB * NN / 64) * 4, 256, 0, stream>>>(ws_msgs, out_w, out_b,
                                                         recv, newbuf);
    bq2_kernel<<<(NN * BB / 64) * 4, 256, 0, stream>>>(hmat, ws_wqk, ws_wqb,
                                                       ws_bq2);
    temporal_kernel<<<NN * BB / 4, 256, 0, stream>>>(bufs, ws_bq2, dlog,
                                                     newbuf, ws_acc, ws_s);
    readout_kernel<<<(NN * BB / 64) * 4, 256, 0, stream>>>(ws_acc, bv_w, ws_s,
                                                           bv_b, readout);
}